// Round 9
// baseline (172.445 us; speedup 1.0000x reference)
//
#include <hip/hip_runtime.h>
#include <hip/hip_bf16.h>

#define SDIM 2048
#define BATCH 4
#define DMODEL 512
#define NH 8
#define NKV 2
#define HD 64

typedef __bf16 bf16x8 __attribute__((ext_vector_type(8)));
typedef float floatx16 __attribute__((ext_vector_type(16)));
typedef unsigned short u16;
typedef unsigned int u32;

#define MFMA32 __builtin_amdgcn_mfma_f32_32x32x16_bf16
#define ZERO16 {0.f,0.f,0.f,0.f,0.f,0.f,0.f,0.f,0.f,0.f,0.f,0.f,0.f,0.f,0.f,0.f}
// softmax scale with log2(e) folded: exp(s*0.125) = exp2(s*0.125*log2e)
#define QSCALE 0.18033688011112042f

__device__ __forceinline__ u16 f2bf(float f) {
  union { float f; u32 u; } a; a.f = f;
  u32 r = a.u + 0x7fffu + ((a.u >> 16) & 1u);
  return (u16)(r >> 16);
}
// pack two f32 -> (lo, hi) bf16 pair via v_cvt_pk_bf16_f32
__device__ __forceinline__ u32 pkbf(float lo, float hi) {
  __hip_bfloat162 h = __float22bfloat162_rn(float2{lo, hi});
  union { __hip_bfloat162 h; u32 u; } c; c.h = h;
  return c.u;
}

// ---- fused conversions: x fp32->bf16 (blocks 0..4095), weights -> WT[1280][512]
// bf16 transposed (blocks 4096..6655) ----
__global__ __launch_bounds__(256) void cvt_kernel(const float* __restrict__ x,
                                                  const float* __restrict__ Wq,
                                                  const float* __restrict__ Wk,
                                                  const float* __restrict__ Wv,
                                                  const float* __restrict__ Wo,
                                                  u16* __restrict__ xb,
                                                  u16* __restrict__ WT) {
  int bid = blockIdx.x;
  if (bid < 4096) {
    int i = bid * 256 + threadIdx.x;
    float4 v = reinterpret_cast<const float4*>(x)[i];
    uint2 o = {pkbf(v.x, v.y), pkbf(v.z, v.w)};
    reinterpret_cast<uint2*>(xb)[i] = o;
  } else {
    int i = (bid - 4096) * 256 + threadIdx.x;  // < 1280*512
    int n = i >> 9, k = i & 511;
    float v;
    if (n < 512)       v = Wq[k * 512 + n];
    else if (n < 640)  v = Wk[k * 128 + (n - 512)];
    else if (n < 768)  v = Wv[k * 128 + (n - 640)];
    else               v = Wo[k * 512 + (n - 768)];
    WT[i] = f2bf(v);
  }
}

// ---- fused QKV projection (unchanged from round 8): 64x64 tile, BK=32,
// distance-2 register prefetch, LDS dbuf stride-40, 32x32 MFMA.
// Q scaled by QSCALE; Q/K head-major; V written TRANSPOSED [B,NKV,64,S].
__global__ __launch_bounds__(256, 4) void gemm_qkv_kernel(const u16* __restrict__ A,
                                                          const u16* __restrict__ WT,
                                                          const float* __restrict__ bq,
                                                          const float* __restrict__ bk,
                                                          const float* __restrict__ bv,
                                                          u16* __restrict__ Qb,
                                                          u16* __restrict__ Kb,
                                                          u16* __restrict__ Vt) {
  __shared__ __align__(16) u16 abuf[2][64 * 40];
  __shared__ __align__(16) u16 bbuf[2][64 * 40];
  int tid = threadIdx.x;
  int lane = tid & 63, wave = tid >> 6;
  int l31 = lane & 31, half = lane >> 5;
  int m0 = blockIdx.y * 64;
  int n0 = blockIdx.x * 64;
  int row = tid >> 2, ch = tid & 3;
  const u16* Asrc = A + (size_t)(m0 + row) * DMODEL + ch * 8;
  const u16* Bsrc = WT + (size_t)(n0 + row) * DMODEL + ch * 8;
  int wo = row * 40 + ch * 8;

  bf16x8 rA[2], rB[2];
  rA[0] = *(const bf16x8*)Asrc;
  rB[0] = *(const bf16x8*)Bsrc;
  rA[1] = *(const bf16x8*)(Asrc + 32);
  rB[1] = *(const bf16x8*)(Bsrc + 32);
  *(bf16x8*)(abuf[0] + wo) = rA[0];
  *(bf16x8*)(bbuf[0] + wo) = rB[0];
  __syncthreads();

  floatx16 acc = ZERO16;
  int mw = (wave & 1) * 32, nw = (wave >> 1) * 32;
  for (int it = 0; it < 16; ++it) {
    if (it < 14) {
      rA[it & 1] = *(const bf16x8*)(Asrc + (it + 2) * 32);
      rB[it & 1] = *(const bf16x8*)(Bsrc + (it + 2) * 32);
    }
    const u16* ab = abuf[it & 1];
    const u16* bb = bbuf[it & 1];
#pragma unroll
    for (int ks = 0; ks < 2; ++ks) {
      bf16x8 af = *(const bf16x8*)(ab + (mw + l31) * 40 + (2 * ks + half) * 8);
      bf16x8 bf = *(const bf16x8*)(bb + (nw + l31) * 40 + (2 * ks + half) * 8);
      acc = MFMA32(af, bf, acc, 0, 0, 0);
    }
    if (it < 15) {
      *(bf16x8*)(abuf[(it + 1) & 1] + wo) = rA[(it + 1) & 1];
      *(bf16x8*)(bbuf[(it + 1) & 1] + wo) = rB[(it + 1) & 1];
    }
    __syncthreads();
  }

  int col = n0 + nw + l31;
  int b4 = m0 >> 11;  // batch fixed per block
  if (col >= 640) {
    int lc = col - 640;
    float bl = bv[lc];
    int hkv = lc >> 6, d = lc & 63;
    u16* vrow = Vt + ((size_t)(b4 * NKV + hkv) * HD + d) * SDIM;
#pragma unroll
    for (int g = 0; g < 4; ++g) {
      int s = (m0 + mw + 8 * g + 4 * half) & 2047;
      ushort4 t;
      t.x = f2bf(acc[4 * g + 0] + bl);
      t.y = f2bf(acc[4 * g + 1] + bl);
      t.z = f2bf(acc[4 * g + 2] + bl);
      t.w = f2bf(acc[4 * g + 3] + bl);
      *(ushort4*)(vrow + s) = t;
    }
  } else {
    u16* outp; const float* bias; float scale; int nhreg, lc;
    if (col < 512) { outp = Qb; bias = bq; scale = QSCALE; nhreg = NH;  lc = col; }
    else           { outp = Kb; bias = bk; scale = 1.0f;   nhreg = NKV; lc = col - 512; }
    float bl = bias[lc];
    int h = lc >> 6, d = lc & 63;
    u16* base = outp + ((size_t)(b4 * nhreg + h) * SDIM) * HD + d;
#pragma unroll
    for (int r = 0; r < 16; ++r) {
      int s = (m0 + mw + (r & 3) + 8 * (r >> 2) + 4 * half) & 2047;
      base[(size_t)s * HD] = f2bf((acc[r] + bl) * scale);
    }
  }
}

// ---- O projection (unchanged from round 8) ----
__global__ __launch_bounds__(256, 4) void gemm_out_kernel(const u16* __restrict__ A,
                                                          const u16* __restrict__ WTo,
                                                          const float* __restrict__ bo,
                                                          float* __restrict__ out) {
  __shared__ __align__(16) u16 abuf[2][64 * 40];
  __shared__ __align__(16) u16 bbuf[2][64 * 40];
  int tid = threadIdx.x;
  int lane = tid & 63, wave = tid >> 6;
  int l31 = lane & 31, half = lane >> 5;
  int m0 = blockIdx.y * 64;
  int n0 = blockIdx.x * 64;
  int row = tid >> 2, ch = tid & 3;
  const u16* Asrc = A + (size_t)(m0 + row) * DMODEL + ch * 8;
  const u16* Bsrc = WTo + (size_t)(n0 + row) * DMODEL + ch * 8;
  int wo = row * 40 + ch * 8;

  bf16x8 rA[2], rB[2];
  rA[0] = *(const bf16x8*)Asrc;
  rB[0] = *(const bf16x8*)Bsrc;
  rA[1] = *(const bf16x8*)(Asrc + 32);
  rB[1] = *(const bf16x8*)(Bsrc + 32);
  *(bf16x8*)(abuf[0] + wo) = rA[0];
  *(bf16x8*)(bbuf[0] + wo) = rB[0];
  __syncthreads();

  floatx16 acc = ZERO16;
  int mw = (wave & 1) * 32, nw = (wave >> 1) * 32;
  for (int it = 0; it < 16; ++it) {
    if (it < 14) {
      rA[it & 1] = *(const bf16x8*)(Asrc + (it + 2) * 32);
      rB[it & 1] = *(const bf16x8*)(Bsrc + (it + 2) * 32);
    }
    const u16* ab = abuf[it & 1];
    const u16* bb = bbuf[it & 1];
#pragma unroll
    for (int ks = 0; ks < 2; ++ks) {
      bf16x8 af = *(const bf16x8*)(ab + (mw + l31) * 40 + (2 * ks + half) * 8);
      bf16x8 bf = *(const bf16x8*)(bb + (nw + l31) * 40 + (2 * ks + half) * 8);
      acc = MFMA32(af, bf, acc, 0, 0, 0);
    }
    if (it < 15) {
      *(bf16x8*)(abuf[(it + 1) & 1] + wo) = rA[(it + 1) & 1];
      *(bf16x8*)(bbuf[(it + 1) & 1] + wo) = rB[(it + 1) & 1];
    }
    __syncthreads();
  }

  int n = n0 + nw + l31;
  float bl = bo[n];
#pragma unroll
  for (int r = 0; r < 16; ++r) {
    int m = m0 + mw + (r & 3) + 8 * (r >> 2) + 4 * half;
    out[(size_t)m * DMODEL + n] = acc[r] + bl;
  }
}

// ---- flash attention, S^T formulation (no P LDS round-trip):
// S^T = MFMA(A=K, B=Q) -> P^T in regs (col=q=l31, row=key); PV as O^T = V^T x P^T
// with a single shfl_xor(32) half-exchange building P^T B-frags in registers.
// Block: 256 thr = 4 waves, 64 q-rows; wave-pairs split keys (pair p owns keys
// p*1024..+1023, 16 iters x 64 keys), partials merged via LDS at the end.
// Grid (32,32) = 1024 blocks -> 4 blocks/CU, 16 waves/CU. LDS 36 KB, 0-conflict
// stride-72 tiles. No-max softmax via v_exp2 (log2e folded into Q scale).
__global__ __launch_bounds__(256, 4) void attn_kernel(const u16* __restrict__ Q,
                                                      const u16* __restrict__ K,
                                                      const u16* __restrict__ Vt,
                                                      u16* __restrict__ O) {
  __shared__ __align__(16) u16 kb[2][64 * 72];
  __shared__ __align__(16) u16 vb[2][64 * 72];
  int tid = threadIdx.x;
  int lane = tid & 63, w = tid >> 6;
  int l31 = lane & 31, half = lane >> 5;
  int s = w & 1, p = w >> 1;
  int bh = blockIdx.y;
  int b = bh >> 3, h = bh & 7, kv = h >> 2;
  int q0 = blockIdx.x * 64;
  const u16* Qh = Q + (size_t)(b * NH + h) * SDIM * HD;
  const u16* Kh = K + (size_t)(b * NKV + kv) * SDIM * HD + (size_t)p * 1024 * HD;
  const u16* Vh = Vt + (size_t)(b * NKV + kv) * HD * SDIM + p * 1024;

  // Q B-frags (held in regs): n = l31 -> q row q0+s*32+l31, k = ks*16+half*8
  bf16x8 qb[4];
#pragma unroll
  for (int ks = 0; ks < 4; ++ks)
    qb[ks] = *(const bf16x8*)(Qh + (size_t)(q0 + s * 32 + l31) * HD + ks * 16 + half * 8);

  // staging (per pair, 128 threads): K rows = keys (natural); V LDS row rv <-> d =
  // 2*(rv&31)+(rv>>5) (even/odd interleave so o0/o1 cover adjacent d)
  int ptid = tid & 127;
  int rr = ptid >> 3, ch = ptid & 7;  // rr 0..15
  const u16* K0 = Kh + (size_t)rr * HD + ch * 8;            // rows rr+16j: +1024j
  const u16* V0 = Vh + (size_t)(2 * rr) * SDIM + ch * 8;    // d for j: 2rr,2rr+32,2rr+1,2rr+33
  int w0 = rr * 72 + ch * 8;                                 // +16*72*j
  u16* kbp = kb[p];
  u16* vbp = vb[p];

  bf16x8 sK0 = *(const bf16x8*)(K0);
  bf16x8 sK1 = *(const bf16x8*)(K0 + 1024);
  bf16x8 sK2 = *(const bf16x8*)(K0 + 2048);
  bf16x8 sK3 = *(const bf16x8*)(K0 + 3072);
  bf16x8 sV0 = *(const bf16x8*)(V0);
  bf16x8 sV1 = *(const bf16x8*)(V0 + (size_t)32 * SDIM);
  bf16x8 sV2 = *(const bf16x8*)(V0 + (size_t)1 * SDIM);
  bf16x8 sV3 = *(const bf16x8*)(V0 + (size_t)33 * SDIM);
  *(bf16x8*)(kbp + w0) = sK0;           *(bf16x8*)(kbp + w0 + 1152) = sK1;
  *(bf16x8*)(kbp + w0 + 2304) = sK2;    *(bf16x8*)(kbp + w0 + 3456) = sK3;
  *(bf16x8*)(vbp + w0) = sV0;           *(bf16x8*)(vbp + w0 + 1152) = sV1;
  *(bf16x8*)(vbp + w0 + 2304) = sV2;    *(bf16x8*)(vbp + w0 + 3456) = sV3;
  __syncthreads();

  floatx16 o0 = ZERO16, o1 = ZERO16;  // O^T tiles: even d / odd d, col q=l31
  float sm = 0.0f;                    // partial row-sum for q (this lane's keys)

  for (int it = 0; it < 16; ++it) {
    if (it < 15) {
      const u16* Kn = K0 + (it + 1) * 4096;
      sK0 = *(const bf16x8*)(Kn);
      sK1 = *(const bf16x8*)(Kn + 1024);
      sK2 = *(const bf16x8*)(Kn + 2048);
      sK3 = *(const bf16x8*)(Kn + 3072);
      const u16* Vn = V0 + (it + 1) * 64;
      sV0 = *(const bf16x8*)(Vn);
      sV1 = *(const bf16x8*)(Vn + (size_t)32 * SDIM);
      sV2 = *(const bf16x8*)(Vn + (size_t)1 * SDIM);
      sV3 = *(const bf16x8*)(Vn + (size_t)33 * SDIM);
    }

#pragma unroll
    for (int seg = 0; seg < 2; ++seg) {   // seg 0: keys 0..31 rows; seg 1: rows 32..63
      // S^T: A = K rows (seg*32 + l31), B = Q
      floatx16 sa = ZERO16;
#pragma unroll
      for (int ks = 0; ks < 4; ++ks) {
        bf16x8 kf = *(const bf16x8*)(kbp + (seg * 32 + l31) * 72 + ks * 16 + half * 8);
        sa = MFMA32(kf, qb[ks], sa, 0, 0, 0);
      }
      float pa[16];
#pragma unroll
      for (int r = 0; r < 16; ++r) {
        pa[r] = __builtin_amdgcn_exp2f(sa[r]);
        sm += pa[r];
      }
      // exchange + PV for the two 16-key windows of this segment
#pragma unroll
      for (int kc = 0; kc < 2; ++kc) {
        u32 pkL0 = pkbf(pa[8 * kc + 0], pa[8 * kc + 1]);
        u32 pkL1 = pkbf(pa[8 * kc + 2], pa[8 * kc + 3]);
        u32 pkH0 = pkbf(pa[8 * kc + 4], pa[8 * kc + 5]);
        u32 pkH1 = pkbf(pa[8 * kc + 6], pa[8 * kc + 7]);
        u32 snd0 = half ? pkL0 : pkH0;
        u32 snd1 = half ? pkL1 : pkH1;
        u32 rcv0 = (u32)__shfl_xor((int)snd0, 32);
        u32 rcv1 = (u32)__shfl_xor((int)snd1, 32);
        union { uint4 u; bf16x8 v; } pf;
        pf.u.x = half ? rcv0 : pkL0;
        pf.u.y = half ? rcv1 : pkL1;
        pf.u.z = half ? pkH0 : rcv0;
        pf.u.w = half ? pkH1 : rcv1;
        int co = (seg * 2 + kc) * 16 + half * 8;   // key window within the 64-key tile
        bf16x8 vf0 = *(const bf16x8*)(vbp + l31 * 72 + co);
        bf16x8 vf1 = *(const bf16x8*)(vbp + (32 + l31) * 72 + co);
        o0 = MFMA32(vf0, pf.v, o0, 0, 0, 0);
        o1 = MFMA32(vf1, pf.v, o1, 0, 0, 0);
      }
    }

    __syncthreads();  // all waves done reading this pair's tiles
    if (it < 15) {
      *(bf16x8*)(kbp + w0) = sK0;           *(bf16x8*)(kbp + w0 + 1152) = sK1;
      *(bf16x8*)(kbp + w0 + 2304) = sK2;    *(bf16x8*)(kbp + w0 + 3456) = sK3;
      *(bf16x8*)(vbp + w0) = sV0;           *(bf16x8*)(vbp + w0 + 1152) = sV1;
      *(bf16x8*)(vbp + w0 + 2304) = sV2;    *(bf16x8*)(vbp + w0 + 3456) = sV3;
    }
    __syncthreads();
  }

  // pair-local total row sum for q (other key-rows live in lane^32, same q)
  sm += __shfl_xor(sm, 32);

  // cross-pair combine through LDS (reuse kb: 128 slots x 36 floats = 18432 B)
  __syncthreads();
  float* cmb = (float*)kb;
  int idx = (s * 64 + half * 32 + l31) * 36;
  if (p == 1) {
#pragma unroll
    for (int g = 0; g < 4; ++g) {
      *(float4*)(cmb + idx + 4 * g)      = float4{o0[4 * g], o0[4 * g + 1], o0[4 * g + 2], o0[4 * g + 3]};
      *(float4*)(cmb + idx + 16 + 4 * g) = float4{o1[4 * g], o1[4 * g + 1], o1[4 * g + 2], o1[4 * g + 3]};
    }
    cmb[idx + 32] = sm;
  }
  __syncthreads();
  if (p == 0) {
#pragma unroll
    for (int g = 0; g < 4; ++g) {
      float4 a = *(const float4*)(cmb + idx + 4 * g);
      float4 c = *(const float4*)(cmb + idx + 16 + 4 * g);
      o0[4 * g] += a.x; o0[4 * g + 1] += a.y; o0[4 * g + 2] += a.z; o0[4 * g + 3] += a.w;
      o1[4 * g] += c.x; o1[4 * g + 1] += c.y; o1[4 * g + 2] += c.z; o1[4 * g + 3] += c.w;
    }
    float inv = 1.0f / (sm + cmb[idx + 32]);
    // lane holds q = q0+s*32+l31 fixed; d = 2*m, 2*m+1 with m = (r&3)+8*(r>>2)+4*half
    u32* dst = (u32*)O + (((size_t)(b * SDIM + q0 + s * 32 + l31)) * DMODEL + h * HD) / 2;
#pragma unroll
    for (int g = 0; g < 4; ++g) {
      uint4 t;
      t.x = pkbf(o0[4 * g + 0] * inv, o1[4 * g + 0] * inv);
      t.y = pkbf(o0[4 * g + 1] * inv, o1[4 * g + 1] * inv);
      t.z = pkbf(o0[4 * g + 2] * inv, o1[4 * g + 2] * inv);
      t.w = pkbf(o0[4 * g + 3] * inv, o1[4 * g + 3] * inv);
      *(uint4*)(dst + 8 * g + 4 * half) = t;
    }
  }
}

extern "C" void kernel_launch(void* const* d_in, const int* in_sizes, int n_in,
                              void* d_out, int out_size, void* d_ws, size_t ws_size,
                              hipStream_t stream) {
  const float* x  = (const float*)d_in[0];
  const float* Wq = (const float*)d_in[1];
  const float* bq = (const float*)d_in[2];
  const float* Wk = (const float*)d_in[3];
  const float* bk = (const float*)d_in[4];
  const float* Wv = (const float*)d_in[5];
  const float* bv = (const float*)d_in[6];
  const float* Wo = (const float*)d_in[7];
  const float* bo = (const float*)d_in[8];
  float* out = (float*)d_out;

  const size_t M = (size_t)BATCH * SDIM;  // 8192
  u16* xb  = (u16*)d_ws;                  // 8192*512
  u16* WT  = xb  + M * DMODEL;            // 1280*512
  u16* Qb  = WT  + 1280 * DMODEL;         // 8192*512  [B,NH,S,64]
  u16* Kb  = Qb  + M * DMODEL;            // 8192*128  [B,NKV,S,64]
  u16* VtB = Kb  + M * 128;               // 8192*128  [B,NKV,64,S]
  u16* Ab  = VtB + M * 128;               // 8192*512  [B,S,512]

  cvt_kernel<<<4096 + 2560, 256, 0, stream>>>(x, Wq, Wk, Wv, Wo, xb, WT);
  gemm_qkv_kernel<<<dim3(768 / 64, M / 64), 256, 0, stream>>>(xb, WT, bq, bk, bv, Qb, Kb, VtB);
  attn_kernel<<<dim3(SDIM / 64, BATCH * NH), 256, 0, stream>>>(Qb, Kb, VtB, Ab);
  gemm_out_kernel<<<dim3(512 / 64, M / 64), 256, 0, stream>>>(Ab, WT + (size_t)768 * DMODEL, bo, out);
}